// Round 18
// baseline (372.023 us; speedup 1.0000x reference)
//
#include <hip/hip_runtime.h>

#define ALPHA 0.2f
#define BB 4
#define NN 2048
#define IC 256
#define OC 32
#define TI 16                     // i-rows per k3 block (each wave owns 2 rows)

// ---------------------------------------------------------------------------
// Kernel 1 (frozen, r4 form): h = features @ W; f1 = h@a[:OC]; f2 = h@a[OC:]
// ---------------------------------------------------------------------------
__global__ void k1_hproj(const float* __restrict__ feat,
                         const float* __restrict__ W,
                         const float* __restrict__ a,
                         float* __restrict__ h,
                         float* __restrict__ f1,
                         float* __restrict__ f2) {
    __shared__ float s_feat[IC];
    int row = blockIdx.x;           // b*N + n
    int tid = threadIdx.x;          // 0..63
    ((float4*)s_feat)[tid] = ((const float4*)(feat + (size_t)row * IC))[tid];
    __syncthreads();
    if (tid < OC) {
        int c = tid;
        float acc = 0.f;
        #pragma unroll 8
        for (int k = 0; k < IC; ++k)
            acc += s_feat[k] * W[k * OC + c];
        h[(size_t)row * OC + c] = acc;
        float v1 = acc * a[c];
        float v2 = acc * a[OC + c];
        #pragma unroll
        for (int m = 16; m >= 1; m >>= 1) {
            v1 += __shfl_xor(v1, m, 64);
            v2 += __shfl_xor(v2, m, 64);
        }
        if (c == 0) { f1[row] = v1; f2[row] = v2; }
    }
}

// ---------------------------------------------------------------------------
// Kernel 2 (frozen, r13/r14 form): mask-gated cij with -1e30 sentinel.
// ---------------------------------------------------------------------------
__global__ void k2_cij_masked(const float* __restrict__ distance,
                              const float* __restrict__ We,
                              const int* __restrict__ adj,
                              float* __restrict__ cij) {
    __shared__ unsigned short s_idx[4][512];   // 4 KB
    __shared__ int s_cnt[4];
    __shared__ float s_crow[NN];               // 8 KB
    int i    = blockIdx.x;
    int tid  = threadIdx.x;        // 0..255
    int wv   = tid >> 6;
    int lane = tid & 63;
    const int* arow = adj + (size_t)i * NN;

    int base = 0;
    #pragma unroll
    for (int k = 0; k < 8; ++k) {
        int j = wv * 512 + k * 64 + lane;
        bool m = (arow[j] > 0) || (j == i);
        unsigned long long bal = __ballot(m);
        int pos = __popcll(bal & ((1ull << lane) - 1ull));
        if (m) s_idx[wv][base + pos] = (unsigned short)j;
        base += __popcll(bal);
    }
    if (lane == 0) s_cnt[wv] = base;
    #pragma unroll
    for (int q = 0; q < 2; ++q)
        ((float4*)s_crow)[q * 256 + tid] = make_float4(-1e30f, -1e30f, -1e30f, -1e30f);
    __syncthreads();

    int g8 = tid >> 3;             // element slot 0..31
    int r  = tid & 7;
    float4 w = ((const float4*)We)[r];
    const float4* drow = (const float4*)distance + (size_t)i * NN * 8;
    for (int seg = 0; seg < 4; ++seg) {
        int n = s_cnt[seg];
        for (int b2 = 0; b2 < n; b2 += 32) {
            int e = b2 + g8;
            if (e < n) {           // uniform within each 8-lane group
                int j = s_idx[seg][e];
                float4 d = drow[(size_t)j * 8 + r];
                float v = d.x * w.x + d.y * w.y + d.z * w.z + d.w * w.w;
                v += __shfl_xor(v, 1, 64);
                v += __shfl_xor(v, 2, 64);
                v += __shfl_xor(v, 4, 64);
                if (r == 0) s_crow[j] = v;
            }
        }
    }
    __syncthreads();

    float* crow = cij + (size_t)i * NN;
    #pragma unroll
    for (int q = 0; q < 2; ++q)
        ((float4*)crow)[q * 256 + tid] = ((float4*)s_crow)[q * 256 + tid];
}

// ---------------------------------------------------------------------------
// Kernel 3 (TI=16): halves h re-read traffic (256->128 MB). Wave wv owns rows
// {wv, wv+8} (two sequential score passes). s_fin ALIASED into s_p (16 KB
// saved -> 64.1 KB LDS, 2 blocks/CU); extra barrier makes the alias safe.
// f2 read from global (L2-hot, no LDS copy). PV = r17 b64-read structure.
// ---------------------------------------------------------------------------
__global__ __launch_bounds__(512, 4) void k3_attn(
        const float* __restrict__ f1,
        const float* __restrict__ f2,
        const float* __restrict__ h,
        const float* __restrict__ cij,
        float* __restrict__ out) {
    __shared__ _Float16 s_p[TI][NN];       // 64 KB (s_fin aliases into this)
    __shared__ float s_den[TI];
    int bt = blockIdx.x;                   // 0..511
    int b  = bt >> 7;                      // NN/TI = 128 tiles per batch
    int i0 = (bt & 127) * TI;
    int tid = threadIdx.x;                 // 0..511
    int wv = tid >> 6;
    int lane = tid & 63;

    // --- score phase: wave wv handles rows r = wv and wv+8
    const float4* f4row = (const float4*)(f2 + (size_t)b * NN);
    #pragma unroll
    for (int rp = 0; rp < 2; ++rp) {
        int r  = wv + rp * 8;
        int i  = i0 + r;
        float f1i = f1[(size_t)b * NN + i];
        const float4* c4row = (const float4*)(cij + (size_t)i * NN);
        float sc[32];
        float lmax = -1e30f;
        #pragma unroll
        for (int k = 0; k < 8; ++k) {
            int j4 = lane + 64 * k;            // float4 index
            float4 cv = c4row[j4];
            float4 fv = f4row[j4];
            #pragma unroll
            for (int e = 0; e < 4; ++e) {
                float ee = f1i + ((const float*)&fv)[e];
                ee = ee > 0.f ? ee : ALPHA * ee;
                float s = ee + ((const float*)&cv)[e];   // sentinel absorbs ee
                sc[k * 4 + e] = s;
                lmax = fmaxf(lmax, s);
            }
        }
        #pragma unroll
        for (int m = 32; m >= 1; m >>= 1) lmax = fmaxf(lmax, __shfl_xor(lmax, m, 64));
        float lsum = 0.f;
        #pragma unroll
        for (int k = 0; k < 8; ++k) {
            int j4 = lane + 64 * k;
            _Float16 pq[4];
            #pragma unroll
            for (int e = 0; e < 4; ++e) {
                float p = __expf(sc[k * 4 + e] - lmax);
                pq[e] = (_Float16)p;
                lsum += p;
            }
            *(short4*)&s_p[r][j4 * 4] = *(short4*)pq;    // 8B packed store
        }
        #pragma unroll
        for (int m = 32; m >= 1; m >>= 1) lsum += __shfl_xor(lsum, m, 64);
        if (lane == 0) s_den[r] = lsum;
    }
    __syncthreads();

    // --- PV: thread (g, c4) owns 4 consecutive j per iteration
    const float* hb = h + (size_t)b * NN * OC;
    int g  = tid >> 3;          // 0..63
    int c4 = tid & 7;           // 0..7
    float acc[TI][4];
    #pragma unroll
    for (int r = 0; r < TI; ++r) { acc[r][0] = acc[r][1] = acc[r][2] = acc[r][3] = 0.f; }
    #pragma unroll
    for (int k = 0; k < 8; ++k) {
        int jb = 4 * g + 256 * k;           // 4 consecutive j
        float4 hv[4];
        #pragma unroll
        for (int e = 0; e < 4; ++e)
            hv[e] = *(const float4*)(hb + (size_t)(jb + e) * OC + c4 * 4);
        #pragma unroll
        for (int r = 0; r < TI; ++r) {
            short4 praw = *(const short4*)&s_p[r][jb];   // 8B: 4 j's of row r
            const _Float16* pr = (const _Float16*)&praw;
            #pragma unroll
            for (int e = 0; e < 4; ++e) {
                float p = (float)pr[e];
                acc[r][0] += p * hv[e].x;
                acc[r][1] += p * hv[e].y;
                acc[r][2] += p * hv[e].z;
                acc[r][3] += p * hv[e].w;
            }
        }
    }
    #pragma unroll
    for (int r = 0; r < TI; ++r) {
        #pragma unroll
        for (int q = 0; q < 4; ++q) {
            float v = acc[r][q];
            v += __shfl_xor(v, 8, 64);
            v += __shfl_xor(v, 16, 64);
            v += __shfl_xor(v, 32, 64);
            acc[r][q] = v;
        }
    }
    __syncthreads();            // ALL s_p reads complete before aliased write
    float* s_fin = (float*)&s_p[0][0];     // [wq][c4][r][q] = 8x8x16x4 floats
    if ((tid & 56) == 0) {      // lanes 0..7 of each wave (lane == c4)
        #pragma unroll
        for (int r = 0; r < TI; ++r)
            #pragma unroll
            for (int q = 0; q < 4; ++q)
                s_fin[(((wv * 8 + c4) * TI) + r) * 4 + q] = acc[r][q];
    }
    __syncthreads();
    {                            // all 512 threads: (r, c) output
        int r = tid >> 5, c = tid & 31;
        float v = 0.f;
        #pragma unroll
        for (int wq = 0; wq < 8; ++wq)
            v += s_fin[(((wq * 8 + (c >> 2)) * TI) + r) * 4 + (c & 3)];
        out[((size_t)b * NN + i0 + r) * OC + c] = v / s_den[r];
    }
}

extern "C" void kernel_launch(void* const* d_in, const int* in_sizes, int n_in,
                              void* d_out, int out_size, void* d_ws, size_t ws_size,
                              hipStream_t stream) {
    const float* feat     = (const float*)d_in[0];  // [B,N,IC]
    const float* W        = (const float*)d_in[1];  // [IC,OC]
    const float* a        = (const float*)d_in[2];  // [2*OC,1]
    const float* We       = (const float*)d_in[3];  // [OC,1]
    const float* distance = (const float*)d_in[4];  // [N,N,OC]
    const int*   adj      = (const int*)d_in[5];    // [N,N]
    float* out = (float*)d_out;

    float* ws  = (float*)d_ws;
    float* h   = ws;                       // B*N*OC
    float* f1  = h  + (size_t)BB * NN * OC;
    float* f2  = f1 + (size_t)BB * NN;
    float* cij = f2 + (size_t)BB * NN;     // N*N

    k1_hproj<<<BB * NN, 64, 0, stream>>>(feat, W, a, h, f1, f2);
    k2_cij_masked<<<NN, 256, 0, stream>>>(distance, We, adj, cij);
    k3_attn<<<BB * NN / TI, 512, 0, stream>>>(f1, f2, h, cij, out);
}

// Round 19
// 103.388 us; speedup vs baseline: 3.5983x; 3.5983x over previous
//
#include <hip/hip_runtime.h>

#define ALPHA 0.2f
#define BB 4
#define NN 2048
#define IC 256
#define OC 32
#define TI 8                      // i-rows per k3 block (one wave per row; TI=16 spilled, r18)

// ---------------------------------------------------------------------------
// Kernel 1 (frozen, r4 form): h = features @ W; f1 = h@a[:OC]; f2 = h@a[OC:]
// ---------------------------------------------------------------------------
__global__ void k1_hproj(const float* __restrict__ feat,
                         const float* __restrict__ W,
                         const float* __restrict__ a,
                         float* __restrict__ h,
                         float* __restrict__ f1,
                         float* __restrict__ f2) {
    __shared__ float s_feat[IC];
    int row = blockIdx.x;           // b*N + n
    int tid = threadIdx.x;          // 0..63
    ((float4*)s_feat)[tid] = ((const float4*)(feat + (size_t)row * IC))[tid];
    __syncthreads();
    if (tid < OC) {
        int c = tid;
        float acc = 0.f;
        #pragma unroll 8
        for (int k = 0; k < IC; ++k)
            acc += s_feat[k] * W[k * OC + c];
        h[(size_t)row * OC + c] = acc;
        float v1 = acc * a[c];
        float v2 = acc * a[OC + c];
        #pragma unroll
        for (int m = 16; m >= 1; m >>= 1) {
            v1 += __shfl_xor(v1, m, 64);
            v2 += __shfl_xor(v2, m, 64);
        }
        if (c == 0) { f1[row] = v1; f2[row] = v2; }
    }
}

// ---------------------------------------------------------------------------
// Kernel 2 (frozen, r13/r14 form): mask-gated cij with -1e30 sentinel.
// ---------------------------------------------------------------------------
__global__ void k2_cij_masked(const float* __restrict__ distance,
                              const float* __restrict__ We,
                              const int* __restrict__ adj,
                              float* __restrict__ cij) {
    __shared__ unsigned short s_idx[4][512];   // 4 KB
    __shared__ int s_cnt[4];
    __shared__ float s_crow[NN];               // 8 KB
    int i    = blockIdx.x;
    int tid  = threadIdx.x;        // 0..255
    int wv   = tid >> 6;
    int lane = tid & 63;
    const int* arow = adj + (size_t)i * NN;

    int base = 0;
    #pragma unroll
    for (int k = 0; k < 8; ++k) {
        int j = wv * 512 + k * 64 + lane;
        bool m = (arow[j] > 0) || (j == i);
        unsigned long long bal = __ballot(m);
        int pos = __popcll(bal & ((1ull << lane) - 1ull));
        if (m) s_idx[wv][base + pos] = (unsigned short)j;
        base += __popcll(bal);
    }
    if (lane == 0) s_cnt[wv] = base;
    #pragma unroll
    for (int q = 0; q < 2; ++q)
        ((float4*)s_crow)[q * 256 + tid] = make_float4(-1e30f, -1e30f, -1e30f, -1e30f);
    __syncthreads();

    int g8 = tid >> 3;             // element slot 0..31
    int r  = tid & 7;
    float4 w = ((const float4*)We)[r];
    const float4* drow = (const float4*)distance + (size_t)i * NN * 8;
    for (int seg = 0; seg < 4; ++seg) {
        int n = s_cnt[seg];
        for (int b2 = 0; b2 < n; b2 += 32) {
            int e = b2 + g8;
            if (e < n) {           // uniform within each 8-lane group
                int j = s_idx[seg][e];
                float4 d = drow[(size_t)j * 8 + r];
                float v = d.x * w.x + d.y * w.y + d.z * w.z + d.w * w.w;
                v += __shfl_xor(v, 1, 64);
                v += __shfl_xor(v, 2, 64);
                v += __shfl_xor(v, 4, 64);
                if (r == 0) s_crow[j] = v;
            }
        }
    }
    __syncthreads();

    float* crow = cij + (size_t)i * NN;
    #pragma unroll
    for (int q = 0; q < 2; ++q)
        ((float4*)crow)[q * 256 + tid] = ((float4*)s_crow)[q * 256 + tid];
}

// ---------------------------------------------------------------------------
// Kernel 3 (frozen, r17 form — session best, ~24 us): sentinel cij, float4
// score phase, packed fp16 p, b64 p-reads in PV (4 consecutive j/thread/iter).
// ---------------------------------------------------------------------------
__global__ void k3_attn(const float* __restrict__ f1,
                        const float* __restrict__ f2,
                        const float* __restrict__ h,
                        const float* __restrict__ cij,
                        float* __restrict__ out) {
    __shared__ _Float16 s_p[TI][NN];       // 32 KB
    __shared__ float s_f2[NN];             // 8 KB
    __shared__ float s_den[TI];
    __shared__ float s_fin[8][8][TI][4];   // 8 KB
    int bt = blockIdx.x;                   // 0..1023
    int b  = bt >> 8;                      // NN/TI = 256 tiles
    int i0 = (bt & 255) * TI;
    int tid = threadIdx.x;                 // 0..511
    int wv = tid >> 6;
    int lane = tid & 63;

    ((float4*)s_f2)[tid] = ((const float4*)(f2 + (size_t)b * NN))[tid];
    __syncthreads();

    {
        int i  = i0 + wv;
        int bi = b * NN + i;
        float f1i = f1[bi];
        const float4* c4row = (const float4*)(cij + (size_t)i * NN);
        const float4* f4row = (const float4*)s_f2;
        float sc[32];
        float lmax = -1e30f;
        #pragma unroll
        for (int k = 0; k < 8; ++k) {
            int j4 = lane + 64 * k;            // float4 index
            float4 cv = c4row[j4];
            float4 fv = f4row[j4];
            #pragma unroll
            for (int e = 0; e < 4; ++e) {
                float ee = f1i + ((const float*)&fv)[e];
                ee = ee > 0.f ? ee : ALPHA * ee;
                float s = ee + ((const float*)&cv)[e];   // sentinel absorbs ee
                sc[k * 4 + e] = s;
                lmax = fmaxf(lmax, s);
            }
        }
        #pragma unroll
        for (int m = 32; m >= 1; m >>= 1) lmax = fmaxf(lmax, __shfl_xor(lmax, m, 64));
        float lsum = 0.f;
        #pragma unroll
        for (int k = 0; k < 8; ++k) {
            int j4 = lane + 64 * k;
            _Float16 pq[4];
            #pragma unroll
            for (int e = 0; e < 4; ++e) {
                float p = __expf(sc[k * 4 + e] - lmax);
                pq[e] = (_Float16)p;
                lsum += p;
            }
            *(short4*)&s_p[wv][j4 * 4] = *(short4*)pq;   // 8B packed store
        }
        #pragma unroll
        for (int m = 32; m >= 1; m >>= 1) lsum += __shfl_xor(lsum, m, 64);
        if (lane == 0) s_den[wv] = lsum;
    }
    __syncthreads();

    const float* hb = h + (size_t)b * NN * OC;
    int g  = tid >> 3;          // 0..63
    int c4 = tid & 7;           // 0..7
    float acc[TI][4];
    #pragma unroll
    for (int r = 0; r < TI; ++r) { acc[r][0] = acc[r][1] = acc[r][2] = acc[r][3] = 0.f; }
    #pragma unroll
    for (int k = 0; k < 8; ++k) {
        int jb = 4 * g + 256 * k;           // 4 consecutive j per iteration
        float4 hv[4];
        #pragma unroll
        for (int e = 0; e < 4; ++e)
            hv[e] = *(const float4*)(hb + (size_t)(jb + e) * OC + c4 * 4);
        #pragma unroll
        for (int r = 0; r < TI; ++r) {
            short4 praw = *(const short4*)&s_p[r][jb];   // 8B: 4 j's of row r
            const _Float16* pr = (const _Float16*)&praw;
            #pragma unroll
            for (int e = 0; e < 4; ++e) {
                float p = (float)pr[e];
                acc[r][0] += p * hv[e].x;
                acc[r][1] += p * hv[e].y;
                acc[r][2] += p * hv[e].z;
                acc[r][3] += p * hv[e].w;
            }
        }
    }
    #pragma unroll
    for (int r = 0; r < TI; ++r) {
        #pragma unroll
        for (int q = 0; q < 4; ++q) {
            float v = acc[r][q];
            v += __shfl_xor(v, 8, 64);
            v += __shfl_xor(v, 16, 64);
            v += __shfl_xor(v, 32, 64);
            acc[r][q] = v;
        }
    }
    if ((tid & 56) == 0) {
        #pragma unroll
        for (int r = 0; r < TI; ++r)
            #pragma unroll
            for (int q = 0; q < 4; ++q)
                s_fin[wv][c4][r][q] = acc[r][q];
    }
    __syncthreads();
    if (tid < TI * OC) {
        int r = tid >> 5, c = tid & 31;
        float v = 0.f;
        #pragma unroll
        for (int wq = 0; wq < 8; ++wq) v += s_fin[wq][c >> 2][r][c & 3];
        out[((size_t)b * NN + i0 + r) * OC + c] = v / s_den[r];
    }
}

extern "C" void kernel_launch(void* const* d_in, const int* in_sizes, int n_in,
                              void* d_out, int out_size, void* d_ws, size_t ws_size,
                              hipStream_t stream) {
    const float* feat     = (const float*)d_in[0];  // [B,N,IC]
    const float* W        = (const float*)d_in[1];  // [IC,OC]
    const float* a        = (const float*)d_in[2];  // [2*OC,1]
    const float* We       = (const float*)d_in[3];  // [OC,1]
    const float* distance = (const float*)d_in[4];  // [N,N,OC]
    const int*   adj      = (const int*)d_in[5];    // [N,N]
    float* out = (float*)d_out;

    float* ws  = (float*)d_ws;
    float* h   = ws;                       // B*N*OC
    float* f1  = h  + (size_t)BB * NN * OC;
    float* f2  = f1 + (size_t)BB * NN;
    float* cij = f2 + (size_t)BB * NN;     // N*N

    k1_hproj<<<BB * NN, 64, 0, stream>>>(feat, W, a, h, f1, f2);
    k2_cij_masked<<<NN, 256, 0, stream>>>(distance, We, adj, cij);
    k3_attn<<<BB * NN / TI, 512, 0, stream>>>(f1, f2, h, cij, out);
}